// Round 1
// baseline (855.107 us; speedup 1.0000x reference)
//
#include <hip/hip_runtime.h>

#define DIM    1024
#define HEADS  16
#define HD     64
#define BATCH  2
#define SEQ    2048
#define SCALE  0.125f

typedef __attribute__((ext_vector_type(8))) short           short8;
typedef __attribute__((ext_vector_type(4))) float           f4;
typedef __attribute__((ext_vector_type(4))) unsigned short  u16x4;
typedef __attribute__((ext_vector_type(4))) unsigned int    u32x4;

__device__ __forceinline__ unsigned short f2bf(float f) {
    unsigned int u = __builtin_bit_cast(unsigned int, f);
    u = (u + 0x7fffu + ((u >> 16) & 1u)) >> 16;   // RNE
    return (unsigned short)u;
}
__device__ __forceinline__ float bf2f(unsigned short h) {
    return __builtin_bit_cast(float, (unsigned int)h << 16);
}

// ---------------- fp32 -> bf16 cast (vectorized, memory-bound) ----------------
__global__ __launch_bounds__(256) void k_cast(const float* __restrict__ in,
                                              unsigned short* __restrict__ out, int n4) {
    int i = blockIdx.x * 256 + threadIdx.x;
    if (i >= n4) return;
    f4 v = ((const f4*)in)[i];
    u16x4 o;
    o[0] = f2bf(v[0]); o[1] = f2bf(v[1]); o[2] = f2bf(v[2]); o[3] = f2bf(v[3]);
    ((u16x4*)out)[i] = o;
}

// ---------------- bf16 NT-GEMM: C[m,n] = sum_k A[m,k]*W[n,k] ----------------
// 128x128 tile, BK=32, 256 threads = 4 waves in 2x2, each wave 4x4 MFMA frags.
// MFMA 16x16x32_bf16: A frag m=lane&15, k=quad*8+j ; C/D col=lane&15, row=quad*4+reg.
// MODE 0: out bf16 scattered to [B,H,SEQ,HD] (QKV).  MODE 1: out fp32 [M,DIM] + bias.
template<int MODE>
__global__ __launch_bounds__(256) void gemm_nt(
    const unsigned short* __restrict__ A,     // [M,1024] bf16 row-major
    const unsigned short* __restrict__ W,     // [N,1024] bf16 row-major
    unsigned short* __restrict__ outb,
    float* __restrict__ outf,
    const float* __restrict__ bias)
{
    __shared__ __align__(16) unsigned short As[128 * 32];
    __shared__ __align__(16) unsigned short Bs[128 * 32];
    const int m0 = blockIdx.y * 128, n0 = blockIdx.x * 128;
    const int tid  = threadIdx.x;
    const int wave = tid >> 6, lane = tid & 63;
    const int quad = lane >> 4, l16 = lane & 15;
    const int wm = (wave & 1) << 6, wn = (wave >> 1) << 6;

    f4 acc[4][4] = {};

    for (int k0 = 0; k0 < DIM; k0 += 32) {
        // stage 128x32 bf16 tiles of A and W (16B per thread per array, x2)
        #pragma unroll
        for (int i = 0; i < 2; i++) {
            int c = tid + (i << 8);
            int row = c >> 2, koff = (c & 3) << 3;
            *(u32x4*)(&As[row * 32 + koff]) = *(const u32x4*)(&A[(size_t)(m0 + row) * DIM + k0 + koff]);
            *(u32x4*)(&Bs[row * 32 + koff]) = *(const u32x4*)(&W[(size_t)(n0 + row) * DIM + k0 + koff]);
        }
        __syncthreads();
        short8 afr[4], bfr[4];
        #pragma unroll
        for (int i = 0; i < 4; i++)
            afr[i] = *(const short8*)(&As[(wm + i * 16 + l16) * 32 + quad * 8]);
        #pragma unroll
        for (int j = 0; j < 4; j++)
            bfr[j] = *(const short8*)(&Bs[(wn + j * 16 + l16) * 32 + quad * 8]);
        #pragma unroll
        for (int i = 0; i < 4; i++) {
            #pragma unroll
            for (int j = 0; j < 4; j++) {
                acc[i][j] = __builtin_amdgcn_mfma_f32_16x16x32_bf16(afr[i], bfr[j], acc[i][j], 0, 0, 0);
            }
        }
        __syncthreads();
    }

    #pragma unroll
    for (int j = 0; j < 4; j++) {
        const int n = n0 + wn + j * 16 + l16;
        const float bv = (MODE == 1) ? bias[n] : 0.0f;
        #pragma unroll
        for (int i = 0; i < 4; i++) {
            #pragma unroll
            for (int r = 0; r < 4; r++) {
                const int m = m0 + wm + i * 16 + quad * 4 + r;
                const float v = acc[i][j][r];
                if (MODE == 0) {
                    const int b = m >> 11, ns = m & (SEQ - 1);
                    const int h = n >> 6,  d  = n & (HD - 1);
                    outb[((size_t)(b * HEADS + h) * SEQ + ns) * HD + d] = f2bf(v);
                } else {
                    outf[(size_t)m * DIM + n] = v + bv;
                }
            }
        }
    }
}

// ---------------- fp32 flash attention, 64-row Q tile per block ----------------
// 256 threads: tx=tid&15 (cols), ty=tid>>4 (4 rows each). K staged TRANSPOSED
// (KsT[d][j]) so S-phase reads are row-contiguous (no stride-272B bank conflicts).
__global__ __launch_bounds__(256) void attn_fwd(
    const unsigned short* __restrict__ Qg,    // [B*H, SEQ, HD] bf16
    const unsigned short* __restrict__ Kg,
    const unsigned short* __restrict__ Vg,
    unsigned short* __restrict__ AOb)         // [B, SEQ, DIM] bf16
{
    __shared__ __align__(16) float Qs[64][68];
    __shared__ __align__(16) float KsT[64][68];
    __shared__ __align__(16) float Vs[64][68];
    __shared__ __align__(16) float Ps[64][68];

    const int bh = blockIdx.y;
    const int q0 = blockIdx.x << 6;
    const unsigned short* Qb = Qg + (size_t)bh * SEQ * HD;
    const unsigned short* Kb = Kg + (size_t)bh * SEQ * HD;
    const unsigned short* Vb = Vg + (size_t)bh * SEQ * HD;
    const int tid = threadIdx.x;
    const int tx = tid & 15, ty = tid >> 4;

    #pragma unroll
    for (int i = 0; i < 4; i++) {
        int c = tid + (i << 8);
        int row = c >> 4, c4 = c & 15;
        u16x4 qv = *(const u16x4*)(&Qb[(size_t)(q0 + row) * HD + c4 * 4]);
        f4 qf = { bf2f(qv[0]), bf2f(qv[1]), bf2f(qv[2]), bf2f(qv[3]) };
        *(f4*)(&Qs[row][c4 * 4]) = qf;
    }

    const f4 vzero = {0.0f, 0.0f, 0.0f, 0.0f};
    float m_i[4], l_i[4];
    f4 Oa[4];
    #pragma unroll
    for (int i = 0; i < 4; i++) { m_i[i] = -1e30f; l_i[i] = 0.0f; Oa[i] = vzero; }

    for (int kt = 0; kt < SEQ / 64; kt++) {
        __syncthreads();
        #pragma unroll
        for (int i = 0; i < 4; i++) {
            int c = tid + (i << 8);
            int row = c >> 4, c4 = c & 15;
            u16x4 kv = *(const u16x4*)(&Kb[(size_t)(kt * 64 + row) * HD + c4 * 4]);
            KsT[c4 * 4 + 0][row] = bf2f(kv[0]);
            KsT[c4 * 4 + 1][row] = bf2f(kv[1]);
            KsT[c4 * 4 + 2][row] = bf2f(kv[2]);
            KsT[c4 * 4 + 3][row] = bf2f(kv[3]);
            u16x4 vv = *(const u16x4*)(&Vb[(size_t)(kt * 64 + row) * HD + c4 * 4]);
            f4 vf = { bf2f(vv[0]), bf2f(vv[1]), bf2f(vv[2]), bf2f(vv[3]) };
            *(f4*)(&Vs[row][c4 * 4]) = vf;
        }
        __syncthreads();

        // S = Q K^T (4x4 micro-tile per thread)
        float s[4][4] = {};
        #pragma unroll
        for (int d4 = 0; d4 < 16; d4++) {
            f4 q[4], k[4];
            #pragma unroll
            for (int i = 0; i < 4; i++)  q[i]  = *(const f4*)(&Qs[ty * 4 + i][d4 * 4]);
            #pragma unroll
            for (int dd = 0; dd < 4; dd++) k[dd] = *(const f4*)(&KsT[d4 * 4 + dd][tx * 4]);
            #pragma unroll
            for (int i = 0; i < 4; i++) {
                #pragma unroll
                for (int j = 0; j < 4; j++) {
                    s[i][j] += q[i][0] * k[0][j] + q[i][1] * k[1][j]
                             + q[i][2] * k[2][j] + q[i][3] * k[3][j];
                }
            }
        }

        // online softmax, per-row state shared across the 16 lanes of a row group
        #pragma unroll
        for (int i = 0; i < 4; i++) {
            float mx = -1e30f;
            #pragma unroll
            for (int j = 0; j < 4; j++) { s[i][j] *= SCALE; mx = fmaxf(mx, s[i][j]); }
            #pragma unroll
            for (int off = 1; off < 16; off <<= 1) mx = fmaxf(mx, __shfl_xor(mx, off));
            const float mn = fmaxf(m_i[i], mx);
            const float al = __expf(m_i[i] - mn);
            float ps = 0.0f;
            #pragma unroll
            for (int j = 0; j < 4; j++) { s[i][j] = __expf(s[i][j] - mn); ps += s[i][j]; }
            #pragma unroll
            for (int off = 1; off < 16; off <<= 1) ps += __shfl_xor(ps, off);
            l_i[i] = l_i[i] * al + ps;
            m_i[i] = mn;
            Oa[i] *= al;
            f4 pv; pv[0] = s[i][0]; pv[1] = s[i][1]; pv[2] = s[i][2]; pv[3] = s[i][3];
            *(f4*)(&Ps[ty * 4 + i][tx * 4]) = pv;
        }
        __syncthreads();

        // O += P V
        #pragma unroll
        for (int j4 = 0; j4 < 16; j4++) {
            f4 v[4], p[4];
            #pragma unroll
            for (int jj = 0; jj < 4; jj++) v[jj] = *(const f4*)(&Vs[j4 * 4 + jj][tx * 4]);
            #pragma unroll
            for (int i = 0; i < 4; i++)    p[i]  = *(const f4*)(&Ps[ty * 4 + i][j4 * 4]);
            #pragma unroll
            for (int i = 0; i < 4; i++) {
                Oa[i] += p[i][0] * v[0] + p[i][1] * v[1] + p[i][2] * v[2] + p[i][3] * v[3];
            }
        }
    }

    const int b = bh >> 4, h = bh & (HEADS - 1);
    #pragma unroll
    for (int i = 0; i < 4; i++) {
        const float inv = 1.0f / l_i[i];
        u16x4 o;
        #pragma unroll
        for (int c = 0; c < 4; c++) o[c] = f2bf(Oa[i][c] * inv);
        *(u16x4*)(&AOb[(size_t)(b * SEQ + q0 + ty * 4 + i) * DIM + h * HD + tx * 4]) = o;
    }
}

// ---------------- launch ----------------
extern "C" void kernel_launch(void* const* d_in, const int* in_sizes, int n_in,
                              void* d_out, int out_size, void* d_ws, size_t ws_size,
                              hipStream_t stream) {
    (void)in_sizes; (void)n_in; (void)out_size; (void)ws_size;
    const float* x  = (const float*)d_in[0];
    const float* Wq = (const float*)d_in[1];
    const float* Wk = (const float*)d_in[2];
    const float* Wv = (const float*)d_in[3];
    const float* Wo = (const float*)d_in[4];
    const float* bo = (const float*)d_in[5];

    // workspace layout (all bf16/ushort elements; 48 MB total)
    unsigned short* wsu = (unsigned short*)d_ws;
    unsigned short* xb  = wsu;                   // x bf16        [4096,1024]  (4M)
    unsigned short* Wqb = wsu + (4u  << 20);     // weights bf16  [1024,1024]  (1M each)
    unsigned short* Wkb = wsu + (5u  << 20);
    unsigned short* Wvb = wsu + (6u  << 20);
    unsigned short* Wob = wsu + (7u  << 20);
    unsigned short* Qb  = wsu + (8u  << 20);     // Q bf16 [B,H,SEQ,HD] (4M)
    unsigned short* Kb  = wsu + (12u << 20);
    unsigned short* Vb  = wsu + (16u << 20);
    unsigned short* AOb = wsu + (20u << 20);     // attn out bf16 [4096,1024] (4M)

    k_cast<<<4096, 256, 0, stream>>>(x,  xb,  1 << 20);
    k_cast<<<1024, 256, 0, stream>>>(Wq, Wqb, 1 << 18);
    k_cast<<<1024, 256, 0, stream>>>(Wk, Wkb, 1 << 18);
    k_cast<<<1024, 256, 0, stream>>>(Wv, Wvb, 1 << 18);
    k_cast<<<1024, 256, 0, stream>>>(Wo, Wob, 1 << 18);

    dim3 gg(DIM / 128, (BATCH * SEQ) / 128);     // (8, 32)
    gemm_nt<0><<<gg, 256, 0, stream>>>(xb, Wqb, Qb, nullptr, nullptr);
    gemm_nt<0><<<gg, 256, 0, stream>>>(xb, Wkb, Kb, nullptr, nullptr);
    gemm_nt<0><<<gg, 256, 0, stream>>>(xb, Wvb, Vb, nullptr, nullptr);

    attn_fwd<<<dim3(SEQ / 64, BATCH * HEADS), 256, 0, stream>>>(Qb, Kb, Vb, AOb);

    gemm_nt<1><<<gg, 256, 0, stream>>>(AOb, Wob, nullptr, (float*)d_out, bo);
}

// Round 2
// 279.566 us; speedup vs baseline: 3.0587x; 3.0587x over previous
//
#include <hip/hip_runtime.h>

#define DIM    1024
#define HEADS  16
#define HD     64
#define BATCH  2
#define SEQ    2048
#define SCALE  0.125f

typedef __attribute__((ext_vector_type(8))) short           short8;
typedef __attribute__((ext_vector_type(4))) float           f4;
typedef __attribute__((ext_vector_type(4))) unsigned short  u16x4;
typedef __attribute__((ext_vector_type(4))) unsigned int    u32x4;

__device__ __forceinline__ unsigned short f2bf(float f) {
    unsigned int u = __builtin_bit_cast(unsigned int, f);
    u = (u + 0x7fffu + ((u >> 16) & 1u)) >> 16;   // RNE
    return (unsigned short)u;
}
__device__ __forceinline__ float bf2f(unsigned short h) {
    return __builtin_bit_cast(float, (unsigned int)h << 16);
}

// ---------------- fp32 -> bf16 cast ----------------
__global__ __launch_bounds__(256) void k_cast(const float* __restrict__ in,
                                              unsigned short* __restrict__ out, int n4) {
    int i = blockIdx.x * 256 + threadIdx.x;
    if (i >= n4) return;
    f4 v = ((const f4*)in)[i];
    u16x4 o;
    o[0] = f2bf(v[0]); o[1] = f2bf(v[1]); o[2] = f2bf(v[2]); o[3] = f2bf(v[3]);
    ((u16x4*)out)[i] = o;
}

// ---------------- bf16 NT-GEMM: C[m,n] = sum_k A[m,k]*W[n,k] ----------------
// MODE 0: out bf16 [B,H,SEQ,HD] (Q,K). MODE 2: out bf16 [B,H,HD,SEQ] (V^T).
// MODE 1: out fp32 [M,DIM] + bias.
template<int MODE>
__global__ __launch_bounds__(256) void gemm_nt(
    const unsigned short* __restrict__ A,     // [M,1024] bf16 row-major
    const unsigned short* __restrict__ W,     // [N,1024] bf16 row-major
    unsigned short* __restrict__ outb,
    float* __restrict__ outf,
    const float* __restrict__ bias)
{
    __shared__ __align__(16) unsigned short As[128 * 32];
    __shared__ __align__(16) unsigned short Bs[128 * 32];
    const int m0 = blockIdx.y * 128, n0 = blockIdx.x * 128;
    const int tid  = threadIdx.x;
    const int wave = tid >> 6, lane = tid & 63;
    const int quad = lane >> 4, l16 = lane & 15;
    const int wm = (wave & 1) << 6, wn = (wave >> 1) << 6;

    f4 acc[4][4] = {};

    for (int k0 = 0; k0 < DIM; k0 += 32) {
        #pragma unroll
        for (int i = 0; i < 2; i++) {
            int c = tid + (i << 8);
            int row = c >> 2, koff = (c & 3) << 3;
            *(u32x4*)(&As[row * 32 + koff]) = *(const u32x4*)(&A[(size_t)(m0 + row) * DIM + k0 + koff]);
            *(u32x4*)(&Bs[row * 32 + koff]) = *(const u32x4*)(&W[(size_t)(n0 + row) * DIM + k0 + koff]);
        }
        __syncthreads();
        short8 afr[4], bfr[4];
        #pragma unroll
        for (int i = 0; i < 4; i++)
            afr[i] = *(const short8*)(&As[(wm + i * 16 + l16) * 32 + quad * 8]);
        #pragma unroll
        for (int j = 0; j < 4; j++)
            bfr[j] = *(const short8*)(&Bs[(wn + j * 16 + l16) * 32 + quad * 8]);
        #pragma unroll
        for (int i = 0; i < 4; i++)
            #pragma unroll
            for (int j = 0; j < 4; j++)
                acc[i][j] = __builtin_amdgcn_mfma_f32_16x16x32_bf16(afr[i], bfr[j], acc[i][j], 0, 0, 0);
        __syncthreads();
    }

    #pragma unroll
    for (int j = 0; j < 4; j++) {
        const int n = n0 + wn + j * 16 + l16;
        const float bv = (MODE == 1) ? bias[n] : 0.0f;
        #pragma unroll
        for (int i = 0; i < 4; i++) {
            #pragma unroll
            for (int r = 0; r < 4; r++) {
                const int m = m0 + wm + i * 16 + quad * 4 + r;
                const float v = acc[i][j][r];
                if (MODE == 0) {
                    const int b = m >> 11, ns = m & (SEQ - 1);
                    const int h = n >> 6,  d  = n & (HD - 1);
                    outb[((size_t)(b * HEADS + h) * SEQ + ns) * HD + d] = f2bf(v);
                } else if (MODE == 2) {
                    const int b = m >> 11, ns = m & (SEQ - 1);
                    const int h = n >> 6,  d  = n & (HD - 1);
                    outb[((size_t)(b * HEADS + h) * HD + d) * SEQ + ns] = f2bf(v);
                } else {
                    outf[(size_t)m * DIM + n] = v + bv;
                }
            }
        }
    }
}

// ---------------- MFMA flash attention ----------------
// Block: 256 thr = 4 waves; Q-tile 128 rows (32/wave), K-tile 64.
// S^T = K·Q^T  (C-layout: col=l16 -> query, row=quad*4+r -> key)
// O^T = V^T·P^T (C-layout: col=l16 -> query, row=quad*4+r -> d)
// All LDS rows padded to 72 bf16 (144 B = 36 banks -> conflict-balanced).
__global__ __launch_bounds__(256) void attn_fwd(
    const unsigned short* __restrict__ Qg,    // [B*H, SEQ, HD] bf16
    const unsigned short* __restrict__ Kg,    // [B*H, SEQ, HD] bf16
    const unsigned short* __restrict__ VTg,   // [B*H, HD, SEQ] bf16 (transposed)
    unsigned short* __restrict__ AOb)         // [B, SEQ, DIM] bf16
{
    __shared__ __align__(16) unsigned short QsP[128 * 72];  // Q staging, then P
    __shared__ __align__(16) unsigned short Ks [64 * 72];
    __shared__ __align__(16) unsigned short VsT[64 * 72];

    const int bh = blockIdx.y;
    const int q0 = blockIdx.x << 7;           // 128-row Q tile
    const unsigned short* Qb  = Qg  + (size_t)bh * SEQ * HD;
    const unsigned short* Kb  = Kg  + (size_t)bh * SEQ * HD;
    const unsigned short* VTb = VTg + (size_t)bh * HD * SEQ;

    const int tid  = threadIdx.x;
    const int wave = tid >> 6, lane = tid & 63;
    const int quad = lane >> 4, l16 = lane & 15;
    const int qw   = wave << 5;               // wave's 32-query block

    // ---- stage Q tile: 128 rows x 64 d ----
    #pragma unroll
    for (int p = 0; p < 4; p++) {
        const int row = (tid >> 3) + p * 32;
        const int dg  = (tid & 7) * 8;
        *(u32x4*)(&QsP[row * 72 + dg]) = *(const u32x4*)(&Qb[(size_t)(q0 + row) * HD + dg]);
    }
    __syncthreads();

    // Q fragments (loop-invariant): B-operand layout B[k=d][n=q] = Q[q][d]
    short8 qf[2][2];
    #pragma unroll
    for (int nf = 0; nf < 2; nf++)
        #pragma unroll
        for (int ks = 0; ks < 2; ks++)
            qf[nf][ks] = *(const short8*)(&QsP[(qw + nf * 16 + l16) * 72 + ks * 32 + quad * 8]);

    float m_i[2] = {-1e30f, -1e30f};
    float l_i[2] = {0.0f, 0.0f};
    f4 Oacc[4][2] = {};                       // [d-frag][q-frag]

    for (int kt = 0; kt < SEQ / 64; kt++) {
        __syncthreads();                      // prev-iter frag reads done
        // ---- stage K (rows) and V^T (rows=d) ----
        #pragma unroll
        for (int p = 0; p < 2; p++) {
            const int r8 = (tid >> 3) + p * 32;
            const int g8 = (tid & 7) * 8;
            *(u32x4*)(&Ks [r8 * 72 + g8]) = *(const u32x4*)(&Kb [(size_t)(kt * 64 + r8) * HD + g8]);
            *(u32x4*)(&VsT[r8 * 72 + g8]) = *(const u32x4*)(&VTb[(size_t)r8 * SEQ + kt * 64 + g8]);
        }
        __syncthreads();

        // ---- S^T = K·Q^T : m=key(4 frags), n=q(2 frags), k=d(2 steps) ----
        f4 sacc[4][2] = {};
        #pragma unroll
        for (int ks = 0; ks < 2; ks++) {
            short8 kfr[4];
            #pragma unroll
            for (int mf = 0; mf < 4; mf++)
                kfr[mf] = *(const short8*)(&Ks[(mf * 16 + l16) * 72 + ks * 32 + quad * 8]);
            #pragma unroll
            for (int mf = 0; mf < 4; mf++)
                #pragma unroll
                for (int nf = 0; nf < 2; nf++)
                    sacc[mf][nf] = __builtin_amdgcn_mfma_f32_16x16x32_bf16(kfr[mf], qf[nf][ks], sacc[mf][nf], 0, 0, 0);
        }

        // ---- online softmax (per query q = qw + nf*16 + l16) ----
        #pragma unroll
        for (int nf = 0; nf < 2; nf++) {
            float mx = -1e30f;
            #pragma unroll
            for (int mf = 0; mf < 4; mf++)
                #pragma unroll
                for (int r = 0; r < 4; r++) {
                    sacc[mf][nf][r] *= SCALE;
                    mx = fmaxf(mx, sacc[mf][nf][r]);
                }
            mx = fmaxf(mx, __shfl_xor(mx, 16));
            mx = fmaxf(mx, __shfl_xor(mx, 32));
            const float mn = fmaxf(m_i[nf], mx);
            const float al = __expf(m_i[nf] - mn);
            float ps = 0.0f;
            #pragma unroll
            for (int mf = 0; mf < 4; mf++) {
                u16x4 pw;
                #pragma unroll
                for (int r = 0; r < 4; r++) {
                    const float p = __expf(sacc[mf][nf][r] - mn);
                    ps += p;
                    pw[r] = f2bf(p);
                }
                // P[q][j]: wave-private rows -> no barrier needed
                *(u16x4*)(&QsP[(qw + nf * 16 + l16) * 72 + mf * 16 + quad * 4]) = pw;
            }
            ps += __shfl_xor(ps, 16);
            ps += __shfl_xor(ps, 32);
            l_i[nf] = l_i[nf] * al + ps;
            m_i[nf] = mn;
            #pragma unroll
            for (int mf = 0; mf < 4; mf++)
                Oacc[mf][nf] *= al;
        }

        // ---- O^T += V^T·P^T : m=d(4 frags), n=q(2 frags), k=j(2 steps) ----
        #pragma unroll
        for (int ks = 0; ks < 2; ks++) {
            short8 vfr[4], pf[2];
            #pragma unroll
            for (int mf = 0; mf < 4; mf++)
                vfr[mf] = *(const short8*)(&VsT[(mf * 16 + l16) * 72 + ks * 32 + quad * 8]);
            #pragma unroll
            for (int nf = 0; nf < 2; nf++)
                pf[nf] = *(const short8*)(&QsP[(qw + nf * 16 + l16) * 72 + ks * 32 + quad * 8]);
            #pragma unroll
            for (int mf = 0; mf < 4; mf++)
                #pragma unroll
                for (int nf = 0; nf < 2; nf++)
                    Oacc[mf][nf] = __builtin_amdgcn_mfma_f32_16x16x32_bf16(vfr[mf], pf[nf], Oacc[mf][nf], 0, 0, 0);
        }
    }

    // ---- epilogue: O[q][d] = Oacc^T / l ----
    const int b = bh >> 4, h = bh & (HEADS - 1);
    #pragma unroll
    for (int nf = 0; nf < 2; nf++) {
        const float inv = 1.0f / l_i[nf];
        const int qg = q0 + qw + nf * 16 + l16;
        #pragma unroll
        for (int mf = 0; mf < 4; mf++) {
            u16x4 o;
            #pragma unroll
            for (int r = 0; r < 4; r++)
                o[r] = f2bf(Oacc[mf][nf][r] * inv);
            *(u16x4*)(&AOb[(size_t)(b * SEQ + qg) * DIM + h * HD + mf * 16 + quad * 4]) = o;
        }
    }
}

// ---------------- launch ----------------
extern "C" void kernel_launch(void* const* d_in, const int* in_sizes, int n_in,
                              void* d_out, int out_size, void* d_ws, size_t ws_size,
                              hipStream_t stream) {
    (void)in_sizes; (void)n_in; (void)out_size; (void)ws_size;
    const float* x  = (const float*)d_in[0];
    const float* Wq = (const float*)d_in[1];
    const float* Wk = (const float*)d_in[2];
    const float* Wv = (const float*)d_in[3];
    const float* Wo = (const float*)d_in[4];
    const float* bo = (const float*)d_in[5];

    unsigned short* wsu = (unsigned short*)d_ws;
    unsigned short* xb  = wsu;                   // x bf16        [4096,1024]
    unsigned short* Wqb = wsu + (4u  << 20);
    unsigned short* Wkb = wsu + (5u  << 20);
    unsigned short* Wvb = wsu + (6u  << 20);
    unsigned short* Wob = wsu + (7u  << 20);
    unsigned short* Qb  = wsu + (8u  << 20);     // [B,H,SEQ,HD]
    unsigned short* Kb  = wsu + (12u << 20);     // [B,H,SEQ,HD]
    unsigned short* VTb = wsu + (16u << 20);     // [B,H,HD,SEQ]
    unsigned short* AOb = wsu + (20u << 20);     // [B,SEQ,DIM]

    k_cast<<<4096, 256, 0, stream>>>(x,  xb,  1 << 20);
    k_cast<<<1024, 256, 0, stream>>>(Wq, Wqb, 1 << 18);
    k_cast<<<1024, 256, 0, stream>>>(Wk, Wkb, 1 << 18);
    k_cast<<<1024, 256, 0, stream>>>(Wv, Wvb, 1 << 18);
    k_cast<<<1024, 256, 0, stream>>>(Wo, Wob, 1 << 18);

    dim3 gg(DIM / 128, (BATCH * SEQ) / 128);     // (8, 32)
    gemm_nt<0><<<gg, 256, 0, stream>>>(xb, Wqb, Qb,  nullptr, nullptr);
    gemm_nt<0><<<gg, 256, 0, stream>>>(xb, Wkb, Kb,  nullptr, nullptr);
    gemm_nt<2><<<gg, 256, 0, stream>>>(xb, Wvb, VTb, nullptr, nullptr);

    attn_fwd<<<dim3(SEQ / 128, BATCH * HEADS), 256, 0, stream>>>(Qb, Kb, VTb, AOb);

    gemm_nt<1><<<gg, 256, 0, stream>>>(AOb, Wob, nullptr, (float*)d_out, bo);
}

// Round 3
// 213.627 us; speedup vs baseline: 4.0028x; 1.3087x over previous
//
#include <hip/hip_runtime.h>

#define DIM    1024
#define HEADS  16
#define HD     64
#define BATCH  2
#define SEQ    2048
#define SCALE  0.125f
#define C2     0.18033688011112042f   // SCALE * log2(e)

typedef __attribute__((ext_vector_type(8))) short           short8;
typedef __attribute__((ext_vector_type(4))) float           f4;
typedef __attribute__((ext_vector_type(4))) unsigned short  u16x4;
typedef __attribute__((ext_vector_type(4))) unsigned int    u32x4;

typedef __attribute__((address_space(3))) unsigned int       as3_u32;
typedef const __attribute__((address_space(1))) unsigned int as1_u32;

__device__ __forceinline__ unsigned short f2bf(float f) {
    unsigned int u = __builtin_bit_cast(unsigned int, f);
    u = (u + 0x7fffu + ((u >> 16) & 1u)) >> 16;   // RNE
    return (unsigned short)u;
}

#if __has_builtin(__builtin_amdgcn_exp2f)
#define EXP2(x) __builtin_amdgcn_exp2f(x)
#else
#define EXP2(x) exp2f(x)
#endif

// async global->LDS, 16B per lane; lds base is the wave-uniform lane-0 target
__device__ __forceinline__ void gl2lds16(const unsigned short* g, unsigned short* l) {
    __builtin_amdgcn_global_load_lds((as1_u32*)g, (as3_u32*)l, 16, 0, 0);
}

// ---------------- fused fp32 -> bf16 cast: x + 4 weights in one launch ----------------
// dst layout contiguous in ws: xb(1M f4) | Wq | Wk | Wv | Wo (256K f4 each)
__global__ __launch_bounds__(256) void k_cast_all(
    const float* __restrict__ x,  const float* __restrict__ wq,
    const float* __restrict__ wk, const float* __restrict__ wv,
    const float* __restrict__ wo, unsigned short* __restrict__ dst)
{
    const int i = blockIdx.x * 256 + threadIdx.x;      // 0 .. 2M-1 (f4 index)
    const float* src;
    int off;
    if (i < (1 << 20))            { src = x;  off = 0; }
    else if (i < (5 << 18))       { src = wq; off = 1 << 20; }
    else if (i < (6 << 18))       { src = wk; off = 5 << 18; }
    else if (i < (7 << 18))       { src = wv; off = 6 << 18; }
    else                          { src = wo; off = 7 << 18; }
    f4 v = ((const f4*)src)[i - off];
    u16x4 o;
    o[0] = f2bf(v[0]); o[1] = f2bf(v[1]); o[2] = f2bf(v[2]); o[3] = f2bf(v[3]);
    ((u16x4*)dst)[i] = o;
}

// ---------------- fused QKV NT-GEMM, 128x128 tile, global_load_lds staging ----------------
// grid (24, 32): blockIdx.x>>3 selects {Wq,Wk,Wv}; Q,K -> [B,H,SEQ,HD]; V -> [B,H,HD,SEQ]
__global__ __launch_bounds__(256) void gemm_qkv(
    const unsigned short* __restrict__ A,     // xb [4096,1024] bf16
    const unsigned short* __restrict__ Wq,
    const unsigned short* __restrict__ Wk,
    const unsigned short* __restrict__ Wv,
    unsigned short* __restrict__ Qo,
    unsigned short* __restrict__ Ko,
    unsigned short* __restrict__ Vo)
{
    __shared__ __align__(16) unsigned short As[128 * 32];
    __shared__ __align__(16) unsigned short Bs[128 * 32];
    const int wsel = blockIdx.x >> 3;
    const unsigned short* W = (wsel == 0) ? Wq : ((wsel == 1) ? Wk : Wv);
    const int m0 = blockIdx.y * 128, n0 = (blockIdx.x & 7) * 128;
    const int tid  = threadIdx.x;
    const int wave = tid >> 6, lane = tid & 63;
    const int quad = lane >> 4, l16 = lane & 15;
    const int wm = (wave & 1) << 6, wn = (wave >> 1) << 6;

    f4 acc[4][4] = {};

    for (int k0 = 0; k0 < DIM; k0 += 32) {
        __syncthreads();                       // prior frag reads done
        #pragma unroll
        for (int i = 0; i < 2; i++) {
            const int c = tid + (i << 8);
            const int row = c >> 2, koff = (c & 3) << 3;
            // LDS byte offset = c*16 -> lane-contiguous per wave chunk
            gl2lds16(&A[(size_t)(m0 + row) * DIM + k0 + koff], &As[(size_t)((i << 8) + (wave << 6)) * 8]);
            gl2lds16(&W[(size_t)(n0 + row) * DIM + k0 + koff], &Bs[(size_t)((i << 8) + (wave << 6)) * 8]);
        }
        __syncthreads();                       // drains vmcnt -> tiles ready
        short8 afr[4], bfr[4];
        #pragma unroll
        for (int i = 0; i < 4; i++)
            afr[i] = *(const short8*)(&As[(wm + i * 16 + l16) * 32 + quad * 8]);
        #pragma unroll
        for (int j = 0; j < 4; j++)
            bfr[j] = *(const short8*)(&Bs[(wn + j * 16 + l16) * 32 + quad * 8]);
        #pragma unroll
        for (int i = 0; i < 4; i++)
            #pragma unroll
            for (int j = 0; j < 4; j++)
                acc[i][j] = __builtin_amdgcn_mfma_f32_16x16x32_bf16(afr[i], bfr[j], acc[i][j], 0, 0, 0);
    }

    unsigned short* out = (wsel == 0) ? Qo : ((wsel == 1) ? Ko : Vo);
    #pragma unroll
    for (int j = 0; j < 4; j++) {
        const int n = n0 + wn + j * 16 + l16;
        const int h = n >> 6, d = n & (HD - 1);
        #pragma unroll
        for (int i = 0; i < 4; i++) {
            #pragma unroll
            for (int r = 0; r < 4; r++) {
                const int m = m0 + wm + i * 16 + quad * 4 + r;
                const int b = m >> 11, ns = m & (SEQ - 1);
                const unsigned short v = f2bf(acc[i][j][r]);
                if (wsel < 2) out[((size_t)(b * HEADS + h) * SEQ + ns) * HD + d] = v;
                else          out[((size_t)(b * HEADS + h) * HD + d) * SEQ + ns] = v;
            }
        }
    }
}

// ---------------- MFMA flash attention, Q-tile 64 (16 queries/wave) ----------------
// grid (32, 32) = 1024 blocks -> 4 blocks/CU.  S^T = K·Q^T, O^T = V^T·P^T.
// LDS rows padded to 72 bf16. Register prefetch of next K/V tile across barrier.
__global__ __launch_bounds__(256) void attn_fwd(
    const unsigned short* __restrict__ Qg,    // [B*H, SEQ, HD]
    const unsigned short* __restrict__ Kg,    // [B*H, SEQ, HD]
    const unsigned short* __restrict__ VTg,   // [B*H, HD, SEQ]
    unsigned short* __restrict__ AOb)         // [B, SEQ, DIM]
{
    __shared__ __align__(16) unsigned short QsP[64 * 72];   // Q staging, then P
    __shared__ __align__(16) unsigned short Ks [64 * 72];
    __shared__ __align__(16) unsigned short VsT[64 * 72];

    const int bh = blockIdx.y;
    const int q0 = blockIdx.x << 6;
    const unsigned short* Qb  = Qg  + (size_t)bh * SEQ * HD;
    const unsigned short* Kb  = Kg  + (size_t)bh * SEQ * HD;
    const unsigned short* VTb = VTg + (size_t)bh * HD * SEQ;

    const int tid  = threadIdx.x;
    const int wave = tid >> 6, lane = tid & 63;
    const int quad = lane >> 4, l16 = lane & 15;
    const int qw   = wave << 4;               // wave's 16-query block
    const int r8   = tid >> 3;                // staging row (0..31) + p*32
    const int g8   = (tid & 7) * 8;           // staging col group

    // ---- stage Q (64x64) and K/V tile 0 ----
    #pragma unroll
    for (int p = 0; p < 2; p++) {
        const int row = r8 + p * 32;
        *(u32x4*)(&QsP[row * 72 + g8]) = *(const u32x4*)(&Qb[(size_t)(q0 + row) * HD + g8]);
        *(u32x4*)(&Ks [row * 72 + g8]) = *(const u32x4*)(&Kb [(size_t)row * HD + g8]);
        *(u32x4*)(&VsT[row * 72 + g8]) = *(const u32x4*)(&VTb[(size_t)row * SEQ + g8]);
    }
    __syncthreads();

    short8 qf[2];
    #pragma unroll
    for (int ks = 0; ks < 2; ks++)
        qf[ks] = *(const short8*)(&QsP[(qw + l16) * 72 + ks * 32 + quad * 8]);

    float m_i = -1e30f, l_i = 0.0f;
    f4 Oacc[4] = {};

    for (int kt = 0; kt < SEQ / 64; kt++) {
        // prefetch next K/V tile into registers (latency overlapped with compute)
        u32x4 kpre[2], vpre[2];
        if (kt < SEQ / 64 - 1) {
            #pragma unroll
            for (int p = 0; p < 2; p++) {
                const int row = r8 + p * 32;
                kpre[p] = *(const u32x4*)(&Kb [(size_t)((kt + 1) * 64 + row) * HD + g8]);
                vpre[p] = *(const u32x4*)(&VTb[(size_t)row * SEQ + (kt + 1) * 64 + g8]);
            }
        }

        // ---- S^T = K·Q^T : m=key (4 frags), k=d (2 steps) ----
        f4 sacc[4] = {};
        #pragma unroll
        for (int ks = 0; ks < 2; ks++) {
            short8 kfr[4];
            #pragma unroll
            for (int mf = 0; mf < 4; mf++)
                kfr[mf] = *(const short8*)(&Ks[(mf * 16 + l16) * 72 + ks * 32 + quad * 8]);
            #pragma unroll
            for (int mf = 0; mf < 4; mf++)
                sacc[mf] = __builtin_amdgcn_mfma_f32_16x16x32_bf16(kfr[mf], qf[ks], sacc[mf], 0, 0, 0);
        }

        // ---- online softmax (raw-domain max, exp2 domain) ----
        float mx = -1e30f;
        #pragma unroll
        for (int mf = 0; mf < 4; mf++)
            #pragma unroll
            for (int r = 0; r < 4; r++)
                mx = fmaxf(mx, sacc[mf][r]);
        mx = fmaxf(mx, __shfl_xor(mx, 16));
        mx = fmaxf(mx, __shfl_xor(mx, 32));
        const float mn = fmaxf(m_i, mx);
        const float al = EXP2((m_i - mn) * C2);
        const float nm = -mn * C2;
        float ps = 0.0f;
        #pragma unroll
        for (int mf = 0; mf < 4; mf++) {
            u16x4 pw;
            #pragma unroll
            for (int r = 0; r < 4; r++) {
                const float p = EXP2(fmaf(sacc[mf][r], C2, nm));
                ps += p;
                pw[r] = f2bf(p);
            }
            // wave-private rows -> no barrier needed
            *(u16x4*)(&QsP[(qw + l16) * 72 + mf * 16 + quad * 4]) = pw;
        }
        ps += __shfl_xor(ps, 16);
        ps += __shfl_xor(ps, 32);
        l_i = l_i * al + ps;
        m_i = mn;
        #pragma unroll
        for (int mf = 0; mf < 4; mf++)
            Oacc[mf] *= al;

        // ---- O^T += V^T·P^T : m=d (4 frags), k=j (2 steps) ----
        #pragma unroll
        for (int ks = 0; ks < 2; ks++) {
            short8 vfr[4];
            #pragma unroll
            for (int mf = 0; mf < 4; mf++)
                vfr[mf] = *(const short8*)(&VsT[(mf * 16 + l16) * 72 + ks * 32 + quad * 8]);
            const short8 pf = *(const short8*)(&QsP[(qw + l16) * 72 + ks * 32 + quad * 8]);
            #pragma unroll
            for (int mf = 0; mf < 4; mf++)
                Oacc[mf] = __builtin_amdgcn_mfma_f32_16x16x32_bf16(vfr[mf], pf, Oacc[mf], 0, 0, 0);
        }

        __syncthreads();                      // all waves done reading Ks/VsT
        if (kt < SEQ / 64 - 1) {
            #pragma unroll
            for (int p = 0; p < 2; p++) {
                const int row = r8 + p * 32;
                *(u32x4*)(&Ks [row * 72 + g8]) = kpre[p];
                *(u32x4*)(&VsT[row * 72 + g8]) = vpre[p];
            }
        }
        __syncthreads();                      // next tile visible
    }

    // ---- epilogue: O[q][d] = Oacc^T / l ----
    const int b = bh >> 4, h = bh & (HEADS - 1);
    const float inv = 1.0f / l_i;
    const int qg = q0 + qw + l16;
    #pragma unroll
    for (int mf = 0; mf < 4; mf++) {
        u16x4 o;
        #pragma unroll
        for (int r = 0; r < 4; r++)
            o[r] = f2bf(Oacc[mf][r] * inv);
        *(u16x4*)(&AOb[(size_t)(b * SEQ + qg) * DIM + h * HD + mf * 16 + quad * 4]) = o;
    }
}

// ---------------- out-projection NT-GEMM, 64x128 tile + bias, fp32 out ----------------
// grid (8, 64) = 512 blocks -> 2 blocks/CU
__global__ __launch_bounds__(256) void gemm_out(
    const unsigned short* __restrict__ A,     // AOb [4096,1024] bf16
    const unsigned short* __restrict__ W,     // Wob [1024,1024] bf16
    float* __restrict__ out,
    const float* __restrict__ bias)
{
    __shared__ __align__(16) unsigned short As[64 * 32];
    __shared__ __align__(16) unsigned short Bs[128 * 32];
    const int m0 = blockIdx.y * 64, n0 = blockIdx.x * 128;
    const int tid  = threadIdx.x;
    const int wave = tid >> 6, lane = tid & 63;
    const int quad = lane >> 4, l16 = lane & 15;
    const int wm = (wave & 1) << 5, wn = (wave >> 1) << 6;

    f4 acc[2][4] = {};

    for (int k0 = 0; k0 < DIM; k0 += 32) {
        __syncthreads();
        gl2lds16(&A[(size_t)(m0 + (tid >> 2)) * DIM + k0 + ((tid & 3) << 3)],
                 &As[(size_t)(wave << 6) * 8]);
        #pragma unroll
        for (int i = 0; i < 2; i++) {
            const int c = tid + (i << 8);
            gl2lds16(&W[(size_t)(n0 + (c >> 2)) * DIM + k0 + ((c & 3) << 3)],
                     &Bs[(size_t)((i << 8) + (wave << 6)) * 8]);
        }
        __syncthreads();
        short8 afr[2], bfr[4];
        #pragma unroll
        for (int i = 0; i < 2; i++)
            afr[i] = *(const short8*)(&As[(wm + i * 16 + l16) * 32 + quad * 8]);
        #pragma unroll
        for (int j = 0; j < 4; j++)
            bfr[j] = *(const short8*)(&Bs[(wn + j * 16 + l16) * 32 + quad * 8]);
        #pragma unroll
        for (int i = 0; i < 2; i++)
            #pragma unroll
            for (int j = 0; j < 4; j++)
                acc[i][j] = __builtin_amdgcn_mfma_f32_16x16x32_bf16(afr[i], bfr[j], acc[i][j], 0, 0, 0);
    }

    #pragma unroll
    for (int j = 0; j < 4; j++) {
        const int n = n0 + wn + j * 16 + l16;
        const float bv = bias[n];
        #pragma unroll
        for (int i = 0; i < 2; i++) {
            #pragma unroll
            for (int r = 0; r < 4; r++) {
                const int m = m0 + wm + i * 16 + quad * 4 + r;
                out[(size_t)m * DIM + n] = acc[i][j][r] + bv;
            }
        }
    }
}

// ---------------- launch ----------------
extern "C" void kernel_launch(void* const* d_in, const int* in_sizes, int n_in,
                              void* d_out, int out_size, void* d_ws, size_t ws_size,
                              hipStream_t stream) {
    (void)in_sizes; (void)n_in; (void)out_size; (void)ws_size;
    const float* x  = (const float*)d_in[0];
    const float* Wq = (const float*)d_in[1];
    const float* Wk = (const float*)d_in[2];
    const float* Wv = (const float*)d_in[3];
    const float* Wo = (const float*)d_in[4];
    const float* bo = (const float*)d_in[5];

    unsigned short* wsu = (unsigned short*)d_ws;
    unsigned short* xb  = wsu;                   // [4096,1024]
    unsigned short* Wqb = wsu + (4u  << 20);
    unsigned short* Wkb = wsu + (5u  << 20);
    unsigned short* Wvb = wsu + (6u  << 20);
    unsigned short* Wob = wsu + (7u  << 20);
    unsigned short* Qb  = wsu + (8u  << 20);     // [B,H,SEQ,HD]
    unsigned short* Kb  = wsu + (12u << 20);     // [B,H,SEQ,HD]
    unsigned short* VTb = wsu + (16u << 20);     // [B,H,HD,SEQ]
    unsigned short* AOb = wsu + (20u << 20);     // [B,SEQ,DIM]

    k_cast_all<<<8192, 256, 0, stream>>>(x, Wq, Wk, Wv, Wo, wsu);

    gemm_qkv<<<dim3(24, 32), 256, 0, stream>>>(xb, Wqb, Wkb, Wvb, Qb, Kb, VTb);

    attn_fwd<<<dim3(SEQ / 64, BATCH * HEADS), 256, 0, stream>>>(Qb, Kb, VTb, AOb);

    gemm_out<<<dim3(8, 64), 256, 0, stream>>>(AOb, Wob, (float*)d_out, bo);
}